// Round 4
// baseline (3916.904 us; speedup 1.0000x reference)
//
#include <hip/hip_runtime.h>
#include <math.h>

typedef unsigned short ushort_t;
typedef __attribute__((ext_vector_type(8))) short bf16x8;   // 8 bf16 bit-patterns (4 VGPRs)
typedef __attribute__((ext_vector_type(4))) float f32x4;

#define SCALE 0.03608439182435161f  // 1/sqrt(768)

__device__ __forceinline__ ushort_t f2bf(float f) {
  unsigned u = __float_as_uint(f);
  return (ushort_t)((u + 0x7FFFu + ((u >> 16) & 1u)) >> 16);  // RNE
}
__device__ __forceinline__ float bf2f(ushort_t h) {
  return __uint_as_float(((unsigned)h) << 16);
}

// ---------------------------------------------------------------------------
// 128x128xK MFMA GEMM, NT form (both operands rows[idx][k], k-contiguous).
// BK=32, 4 waves (2x2), wave = 64x64 = 4x4 frags of 16x16x32 bf16 MFMA.
// LDS XOR-swizzle on 16B granules: granule' = granule ^ ((row>>1)&3).
// AM/BM: 0 = fp32 source split to hi/lo during staging
//        1 = pre-split hi/lo planes (copy); aSplitS: per-s pair-plane layout
//        2 = single bf16 plane (copy)
// EPI:   0 = fp32 store (scaled); 1 = hi/lo bf16 store (zMode = per-s pairs;
//            caller MUST set Clo — for zMode pair-planes Clo = Chi + 393216)
// TRIPLE: hi*hi + hi*lo + lo*hi
// ---------------------------------------------------------------------------
struct MMP {
  const float* Af;
  const ushort_t* Ahi; const ushort_t* Alo;
  long aLd, aZ; int aSplitS;
  const float* Bf;
  const ushort_t* Bhi; const ushort_t* Blo;
  long bLd, bZ;
  float* Cf; float cScale;
  ushort_t* Chi; ushort_t* Clo;
  long cLd, cZ;
  int zMode;
  int K;
};

template <int AM, int BM, int EPI, bool TRIPLE>
__global__ __launch_bounds__(256) void mm(MMP P)
{
  __shared__ ushort_t lds[16384];   // Ah|Al|Bh|Bl, 4096 each (32 KB)
  ushort_t* Ah = lds;
  ushort_t* Al = lds + 4096;
  ushort_t* Bh = lds + 8192;
  ushort_t* Bl = lds + 12288;

  const int tid = threadIdx.x;
  const int z = blockIdx.z;
  int bx = blockIdx.x, by = blockIdx.y;
  if (gridDim.z == 1) {                       // XCD-aware swizzle (bijective)
    int nwg = gridDim.x * gridDim.y;
    if ((nwg & 7) == 0) {
      int id = by * gridDim.x + bx;
      int q = nwg >> 3;
      int wid = (id & 7) * q + (id >> 3);
      bx = wid % gridDim.x;
      by = wid / gridDim.x;
    }
  }
  const int m0 = by * 128, n0 = bx * 128;

  const int lane = tid & 63;
  const int wave = tid >> 6;
  const int wm = (wave >> 1) * 64, wn = (wave & 1) * 64;
  const int lr = lane & 15, g = lane >> 4;

  f32x4 acc[4][4];
  #pragma unroll
  for (int i = 0; i < 4; ++i)
    #pragma unroll
    for (int j = 0; j < 4; ++j) {
      f32x4 zv = {0.f, 0.f, 0.f, 0.f};
      acc[i][j] = zv;
    }

  for (int k0 = 0; k0 < P.K; k0 += 32) {
    // ---------------- stage A ----------------
    if constexpr (AM == 0) {
      const float* A = P.Af + (long)z * P.aZ;
      #pragma unroll
      for (int rep = 0; rep < 4; ++rep) {
        int idx = tid + rep * 256;
        int row = idx >> 3, q = idx & 7;
        float4 v = *(const float4*)(A + (long)(m0 + row) * P.aLd + k0 + q * 4);
        int off = row * 32 + (((q >> 1) ^ ((row >> 1) & 3)) << 3) + ((q & 1) << 2);
        ushort_t hh[4], ll[4];
        hh[0] = f2bf(v.x); ll[0] = f2bf(v.x - bf2f(hh[0]));
        hh[1] = f2bf(v.y); ll[1] = f2bf(v.y - bf2f(hh[1]));
        hh[2] = f2bf(v.z); ll[2] = f2bf(v.z - bf2f(hh[2]));
        hh[3] = f2bf(v.w); ll[3] = f2bf(v.w - bf2f(hh[3]));
        *(uint2*)(Ah + off) = *(uint2*)hh;
        *(uint2*)(Al + off) = *(uint2*)ll;
      }
    } else if constexpr (AM == 1) {
      #pragma unroll
      for (int rep = 0; rep < 2; ++rep) {
        int idx = tid + rep * 256;
        int row = idx >> 2, h8 = idx & 3;
        int off = row * 32 + ((h8 ^ ((row >> 1) & 3)) << 3);
        int rg = m0 + row;
        const ushort_t *As, *Als;
        if (P.aSplitS) {
          long base = (long)(rg >> 9) * 786432 + (long)(rg & 511) * 768 + k0 + h8 * 8;
          As = P.Ahi + base; Als = P.Ahi + base + 393216;
        } else {
          long base = (long)rg * P.aLd + k0 + h8 * 8;
          As = P.Ahi + (long)z * P.aZ + base;
          Als = P.Alo + (long)z * P.aZ + base;
        }
        *(uint4*)(Ah + off) = *(const uint4*)As;
        *(uint4*)(Al + off) = *(const uint4*)Als;
      }
    } else {
      const ushort_t* As = P.Ahi + (long)z * P.aZ;
      #pragma unroll
      for (int rep = 0; rep < 2; ++rep) {
        int idx = tid + rep * 256;
        int row = idx >> 2, h8 = idx & 3;
        int off = row * 32 + ((h8 ^ ((row >> 1) & 3)) << 3);
        *(uint4*)(Ah + off) = *(const uint4*)(As + (long)(m0 + row) * P.aLd + k0 + h8 * 8);
      }
    }
    // ---------------- stage B ----------------
    if constexpr (BM == 0) {
      const float* B = P.Bf + (long)z * P.bZ;
      #pragma unroll
      for (int rep = 0; rep < 4; ++rep) {
        int idx = tid + rep * 256;
        int row = idx >> 3, q = idx & 7;
        float4 v = *(const float4*)(B + (long)(n0 + row) * P.bLd + k0 + q * 4);
        int off = row * 32 + (((q >> 1) ^ ((row >> 1) & 3)) << 3) + ((q & 1) << 2);
        ushort_t hh[4], ll[4];
        hh[0] = f2bf(v.x); ll[0] = f2bf(v.x - bf2f(hh[0]));
        hh[1] = f2bf(v.y); ll[1] = f2bf(v.y - bf2f(hh[1]));
        hh[2] = f2bf(v.z); ll[2] = f2bf(v.z - bf2f(hh[2]));
        hh[3] = f2bf(v.w); ll[3] = f2bf(v.w - bf2f(hh[3]));
        *(uint2*)(Bh + off) = *(uint2*)hh;
        *(uint2*)(Bl + off) = *(uint2*)ll;
      }
    } else {
      const ushort_t* Bs = P.Bhi + (long)z * P.bZ;
      #pragma unroll
      for (int rep = 0; rep < 2; ++rep) {
        int idx = tid + rep * 256;
        int row = idx >> 2, h8 = idx & 3;
        int off = row * 32 + ((h8 ^ ((row >> 1) & 3)) << 3);
        long gsrc = (long)(n0 + row) * P.bLd + k0 + h8 * 8;
        *(uint4*)(Bh + off) = *(const uint4*)(Bs + gsrc);
        if constexpr (BM == 1) {
          const ushort_t* Bls = P.Blo + (long)z * P.bZ;
          *(uint4*)(Bl + off) = *(const uint4*)(Bls + gsrc);
        }
      }
    }
    __syncthreads();

    // ---------------- compute ----------------
    bf16x8 ar[4], br[4];
    #pragma unroll
    for (int i = 0; i < 4; ++i) {
      int row = wm + i * 16 + lr;
      ar[i] = *(const bf16x8*)(Ah + row * 32 + ((g ^ ((row >> 1) & 3)) << 3));
    }
    #pragma unroll
    for (int j = 0; j < 4; ++j) {
      int row = wn + j * 16 + lr;
      br[j] = *(const bf16x8*)(Bh + row * 32 + ((g ^ ((row >> 1) & 3)) << 3));
    }
    #pragma unroll
    for (int i = 0; i < 4; ++i)
      #pragma unroll
      for (int j = 0; j < 4; ++j)
        acc[i][j] = __builtin_amdgcn_mfma_f32_16x16x32_bf16(ar[i], br[j], acc[i][j], 0, 0, 0);

    if constexpr (TRIPLE) {
      #pragma unroll
      for (int j = 0; j < 4; ++j) {
        int row = wn + j * 16 + lr;
        bf16x8 blv = *(const bf16x8*)(Bl + row * 32 + ((g ^ ((row >> 1) & 3)) << 3));
        #pragma unroll
        for (int i = 0; i < 4; ++i)
          acc[i][j] = __builtin_amdgcn_mfma_f32_16x16x32_bf16(ar[i], blv, acc[i][j], 0, 0, 0);
      }
      #pragma unroll
      for (int i = 0; i < 4; ++i) {
        int row = wm + i * 16 + lr;
        bf16x8 alv = *(const bf16x8*)(Al + row * 32 + ((g ^ ((row >> 1) & 3)) << 3));
        #pragma unroll
        for (int j = 0; j < 4; ++j)
          acc[i][j] = __builtin_amdgcn_mfma_f32_16x16x32_bf16(alv, br[j], acc[i][j], 0, 0, 0);
      }
    }
    __syncthreads();
  }

  // ---------------- epilogue (C/D: col = lane&15, row = (lane>>4)*4 + reg) ---
  #pragma unroll
  for (int i = 0; i < 4; ++i) {
    #pragma unroll
    for (int j = 0; j < 4; ++j) {
      int colG = n0 + wn + j * 16 + lr;
      #pragma unroll
      for (int r = 0; r < 4; ++r) {
        int rowG = m0 + wm + i * 16 + g * 4 + r;
        float v = acc[i][j][r];
        if constexpr (EPI == 0) {
          P.Cf[(long)z * P.cZ + (long)rowG * P.cLd + colG] = v * P.cScale;
        } else {
          ushort_t hi = f2bf(v);
          ushort_t lo = f2bf(v - bf2f(hi));
          long off;
          if (P.zMode) off = (long)(rowG >> 9) * 786432 + (long)(rowG & 511) * 768 + colG;
          else         off = (long)rowG * P.cLd + colG;
          P.Chi[off] = hi;
          P.Clo[off] = lo;
        }
      }
    }
  }
}

// ---------------------------------------------------------------------------
// fsc: fused scores+softmax. Per s: block owns 64 rows x ALL 512 cols of
// P = softmax(SCALE * Z_s X_s^T). 512 thr = 8 waves, wave w covers cols
// [w*64, w*64+64) -> acc[4][4] frags. Triple product from pre-split planes.
// Cross-wave row max/sum via padded LDS arrays. Emits P bf16 directly.
// ---------------------------------------------------------------------------
__global__ __launch_bounds__(512) void fsc(const ushort_t* __restrict__ Zb,
                                           const ushort_t* __restrict__ Xs,
                                           ushort_t* __restrict__ Pm)
{
  __shared__ ushort_t lds[36864];      // Ah(2048)|Al(2048)|Bh(16384)|Bl(16384) ushorts
  __shared__ float redf[64][12];       // padded: 48B rows, 16B-aligned
  __shared__ float reds[64][12];
  ushort_t* Ah = lds;
  ushort_t* Al = lds + 2048;
  ushort_t* Bh = lds + 4096;
  ushort_t* Bl = lds + 20480;

  const int z = blockIdx.y;
  const ushort_t* Az = Zb + (long)z * 786432;   // Z_s hi; lo at +393216
  const ushort_t* Bz = Xs + (long)z * 786432;   // X_s hi; lo at +393216
  const int m0 = blockIdx.x * 64;

  const int tid = threadIdx.x;
  const int lane = tid & 63;
  const int wave = tid >> 6;       // 0..7
  const int wn = wave * 64;
  const int lr = lane & 15, g = lane >> 4;

  f32x4 acc[4][4];
  #pragma unroll
  for (int i = 0; i < 4; ++i)
    #pragma unroll
    for (int j = 0; j < 4; ++j) {
      f32x4 zv = {0.f, 0.f, 0.f, 0.f};
      acc[i][j] = zv;
    }

  for (int k0 = 0; k0 < 768; k0 += 32) {
    // stage A: 64 rows x 32k, hi+lo: 512 uint4 tasks, 1/thread (wave-uniform split)
    {
      int e = tid & 255;
      int row = e >> 2, h8 = e & 3;
      int off = row * 32 + ((h8 ^ ((row >> 1) & 3)) << 3);
      long src = (long)(m0 + row) * 768 + k0 + h8 * 8;
      if (tid < 256) *(uint4*)(Ah + off) = *(const uint4*)(Az + src);
      else           *(uint4*)(Al + off) = *(const uint4*)(Az + 393216 + src);
    }
    // stage B: 512 rows x 32k, hi+lo: 4096 uint4 tasks, 8/thread
    #pragma unroll
    for (int rep = 0; rep < 8; ++rep) {
      int e = (tid + rep * 512) & 2047;
      int row = e >> 2, h8 = e & 3;
      int off = row * 32 + ((h8 ^ ((row >> 1) & 3)) << 3);
      long src = (long)row * 768 + k0 + h8 * 8;
      if (rep < 4) *(uint4*)(Bh + off) = *(const uint4*)(Bz + src);
      else         *(uint4*)(Bl + off) = *(const uint4*)(Bz + 393216 + src);
    }
    __syncthreads();

    bf16x8 arh[4], arl[4];
    #pragma unroll
    for (int i = 0; i < 4; ++i) {
      int row = i * 16 + lr;
      int off = row * 32 + ((g ^ ((row >> 1) & 3)) << 3);
      arh[i] = *(const bf16x8*)(Ah + off);
      arl[i] = *(const bf16x8*)(Al + off);
    }
    #pragma unroll
    for (int j = 0; j < 4; ++j) {
      int row = wn + j * 16 + lr;
      int off = row * 32 + ((g ^ ((row >> 1) & 3)) << 3);
      bf16x8 bh = *(const bf16x8*)(Bh + off);
      bf16x8 bl = *(const bf16x8*)(Bl + off);
      #pragma unroll
      for (int i = 0; i < 4; ++i) {
        acc[i][j] = __builtin_amdgcn_mfma_f32_16x16x32_bf16(arh[i], bh, acc[i][j], 0, 0, 0);
        acc[i][j] = __builtin_amdgcn_mfma_f32_16x16x32_bf16(arh[i], bl, acc[i][j], 0, 0, 0);
        acc[i][j] = __builtin_amdgcn_mfma_f32_16x16x32_bf16(arl[i], bh, acc[i][j], 0, 0, 0);
      }
    }
    __syncthreads();
  }

  // ---- softmax over full rows (cross-wave via LDS) ----
  float mr[4][4];
  #pragma unroll
  for (int i = 0; i < 4; ++i)
    #pragma unroll
    for (int r = 0; r < 4; ++r) {
      float mx = -3.0e38f;
      #pragma unroll
      for (int j = 0; j < 4; ++j) {
        acc[i][j][r] *= SCALE;
        mx = fmaxf(mx, acc[i][j][r]);
      }
      #pragma unroll
      for (int off = 8; off >= 1; off >>= 1) mx = fmaxf(mx, __shfl_xor(mx, off, 64));
      if (lr == 0) redf[i * 16 + g * 4 + r][wave] = mx;
    }
  __syncthreads();
  #pragma unroll
  for (int i = 0; i < 4; ++i)
    #pragma unroll
    for (int r = 0; r < 4; ++r) {
      int row = i * 16 + g * 4 + r;
      float4 a = *(const float4*)&redf[row][0];
      float4 b = *(const float4*)&redf[row][4];
      mr[i][r] = fmaxf(fmaxf(fmaxf(a.x, a.y), fmaxf(a.z, a.w)),
                       fmaxf(fmaxf(b.x, b.y), fmaxf(b.z, b.w)));
    }
  #pragma unroll
  for (int i = 0; i < 4; ++i)
    #pragma unroll
    for (int r = 0; r < 4; ++r) {
      float s = 0.f;
      #pragma unroll
      for (int j = 0; j < 4; ++j) {
        float e = __expf(acc[i][j][r] - mr[i][r]);
        acc[i][j][r] = e;
        s += e;
      }
      #pragma unroll
      for (int off = 8; off >= 1; off >>= 1) s += __shfl_xor(s, off, 64);
      if (lr == 0) reds[i * 16 + g * 4 + r][wave] = s;
    }
  __syncthreads();
  ushort_t* Pz = Pm + (long)z * 262144 + (long)m0 * 512;
  #pragma unroll
  for (int i = 0; i < 4; ++i)
    #pragma unroll
    for (int r = 0; r < 4; ++r) {
      int row = i * 16 + g * 4 + r;
      float4 a = *(const float4*)&reds[row][0];
      float4 b = *(const float4*)&reds[row][4];
      float inv = 1.0f / (a.x + a.y + a.z + a.w + b.x + b.y + b.z + b.w);
      #pragma unroll
      for (int j = 0; j < 4; ++j)
        Pz[(long)row * 512 + wn + j * 16 + lr] = f2bf(acc[i][j][r] * inv);
    }
}

// ---------------------------------------------------------------------------
// prep: per s, split X -> (hi,lo) bf16 pair-planes AND write V^T hi-plane.
// One read of X serves both. 64x64 tiles.
// ---------------------------------------------------------------------------
__global__ __launch_bounds__(256) void prep(const float* __restrict__ X,
                                            ushort_t* __restrict__ Xsp,
                                            ushort_t* __restrict__ Xt, int s0)
{
  const int si = blockIdx.z;
  const long s = s0 + si;
  const int b0 = blockIdx.x * 64, e0 = blockIdx.y * 64;
  __shared__ float tile[64][65];
  const int t = threadIdx.x;
  const int bloc = t >> 4, eq = t & 15;
  ushort_t* Xh = Xsp + (long)si * 786432;
  #pragma unroll
  for (int r = 0; r < 4; ++r) {
    int b = bloc + r * 16;
    float4 v = *(const float4*)(X + (s * 512 + b0 + b) * 768 + e0 + eq * 4);
    tile[b][eq * 4 + 0] = v.x; tile[b][eq * 4 + 1] = v.y;
    tile[b][eq * 4 + 2] = v.z; tile[b][eq * 4 + 3] = v.w;
    ushort_t hh[4], ll[4];
    hh[0] = f2bf(v.x); ll[0] = f2bf(v.x - bf2f(hh[0]));
    hh[1] = f2bf(v.y); ll[1] = f2bf(v.y - bf2f(hh[1]));
    hh[2] = f2bf(v.z); ll[2] = f2bf(v.z - bf2f(hh[2]));
    hh[3] = f2bf(v.w); ll[3] = f2bf(v.w - bf2f(hh[3]));
    long dst = (long)(b0 + b) * 768 + e0 + eq * 4;
    *(uint2*)(Xh + dst)          = *(uint2*)hh;
    *(uint2*)(Xh + 393216 + dst) = *(uint2*)ll;
  }
  __syncthreads();
  const int e = t & 63, bq = t >> 6;
  ushort_t tmp[16];
  #pragma unroll
  for (int i = 0; i < 16; ++i) tmp[i] = f2bf(tile[bq * 16 + i][e]);
  ushort_t* dst = Xt + (long)si * 393216 + (long)(e0 + e) * 512 + b0 + bq * 16;
  *(uint4*)(dst)     = *(uint4*)&tmp[0];
  *(uint4*)(dst + 8) = *(uint4*)&tmp[8];
}

// ---------------------------------------------------------------------------
extern "C" void kernel_launch(void* const* d_in, const int* in_sizes, int n_in,
                              void* d_out, int out_size, void* d_ws, size_t ws_size,
                              hipStream_t stream) {
  const float* X = (const float*)d_in[0];
  const float* R = (const float*)d_in[1];  // rotation_params
  const float* W = (const float*)d_in[2];  // entangle_params
  float* out = (float*)d_out;
  char* ws = (char*)d_ws;

  // ws: H hi/lo (768x768 each) | Xsplit[SCI] pair-planes | Xt[SCI] | Pm[SCI]
  ushort_t* Hhi = (ushort_t*)ws;
  ushort_t* Hlo = Hhi + 768 * 768;
  const size_t hB   = 2ull * 768 * 768 * 2;                      // 2,359,296
  const size_t perS = 786432ull * 2 + 393216ull * 2 + 262144ull * 2;  // 2,883,584
  long SCI = 1;
  if (ws_size > hB + perS) SCI = (long)((ws_size - hB) / perS);
  if (SCI < 1) SCI = 1;
  if (SCI > 512) SCI = 512;
  ushort_t* Xsp = (ushort_t*)(ws + hB);
  ushort_t* Xt  = Xsp + (long)SCI * 786432;
  ushort_t* Pm  = Xt + (long)SCI * 393216;

  // ---- K0: H = W * R^T  (768x768, triple), split-stored hi/lo ----
  {
    MMP p{};
    p.Af = W;  p.aLd = 768; p.aZ = 0;
    p.Bf = R;  p.bLd = 768; p.bZ = 0;
    p.Chi = Hhi; p.Clo = Hlo; p.cLd = 768; p.zMode = 0;
    p.K = 768;
    mm<0, 0, 1, true><<<dim3(6, 6, 1), 256, 0, stream>>>(p);
  }

  for (long s0 = 0; s0 < 512; s0 += SCI) {
    int cur = (int)((512 - s0 < SCI) ? (512 - s0) : SCI);

    // ---- prep: X_s -> split pair-planes + V^T hi-plane ----
    prep<<<dim3(8, 12, cur), 256, 0, stream>>>(X, Xsp, Xt, (int)s0);

    // ---- K1: Z_chunk = X_chunk * H^T (triple) -> d_out pair-planes ----
    {
      MMP p{};
      p.Ahi = Xsp; p.aSplitS = 1; p.aLd = 768; p.aZ = 0;
      p.Bhi = Hhi; p.Blo = Hlo; p.bLd = 768; p.bZ = 0;
      p.Chi = (ushort_t*)d_out + s0 * 786432;
      p.Clo = p.Chi + 393216;   // R3 crash fix: zMode epilogue writes Clo[off] too
      p.zMode = 1;
      p.K = 768;
      mm<1, 1, 1, true><<<dim3(6, 4 * cur, 1), 256, 0, stream>>>(p);
    }

    // ---- fsc: P = softmax(SCALE * Z X^T), fused, bf16 out ----
    fsc<<<dim3(8, cur), 512, 0, stream>>>((const ushort_t*)d_out + s0 * 786432, Xsp, Pm);

    // ---- K4: out_s = P * V (single bf16), overwrites Z_s in d_out ----
    {
      MMP q{};
      q.Ahi = Pm; q.aLd = 512; q.aZ = 262144; q.aSplitS = 0;
      q.Bhi = Xt; q.bLd = 512; q.bZ = 393216;
      q.Cf = out + s0 * 393216; q.cLd = 768; q.cZ = 393216; q.cScale = 1.0f;
      q.K = 512;
      mm<2, 2, 0, false><<<dim3(6, 4, cur), 256, 0, stream>>>(q);
    }
  }
}